// Round 1
// baseline (113.595 us; speedup 1.0000x reference)
//
#include <hip/hip_runtime.h>
#include <math.h>

// Problem shape (fixed by reference): x is (256, 224, 224) f32.
#define HW   50176   // 224*224
#define NV4  12544   // HW/4 float4 per row
#define TPB  1024    // threads per block (one block per row); 12544 = 12*1024 + 256

__device__ __forceinline__ float waveReduceMin(float v) {
#pragma unroll
    for (int o = 32; o > 0; o >>= 1) v = fminf(v, __shfl_down(v, o, 64));
    return v;
}
__device__ __forceinline__ double waveReduceSum(double v) {
#pragma unroll
    for (int o = 32; o > 0; o >>= 1) v += __shfl_down(v, o, 64);
    return v;
}

__device__ __forceinline__ float digamma_f(float x) {
    // shift to >= 6 then asymptotic series; matches jax digamma to ~1e-6
    float r = 0.0f;
    while (x < 6.0f) { r -= 1.0f / x; x += 1.0f; }
    float f = 1.0f / (x * x);
    float ser = f * (1.0f/12.0f - f * (1.0f/120.0f - f * (1.0f/252.0f - f * (1.0f/240.0f - f * (1.0f/132.0f)))));
    return r + logf(x) - 0.5f / x - ser;
}

__device__ __forceinline__ float trigamma_ref(float x) {
    // exact replication of the reference's _trigamma formula
    float z = x + 1.0f;
    float zz = z * z;
    float a = 0.2f - 1.0f / (7.0f * zz);
    float b = 1.0f - a / zz;
    float c = 1.0f + b / (3.0f * z);
    float d = 1.0f + c / (2.0f * z);
    return d / z + 1.0f / (x * x);
}

__global__ void __launch_bounds__(TPB)
gamma_norm2d(const float* __restrict__ x, float* __restrict__ out) {
    const int row = blockIdx.x;
    const int tid = threadIdx.x;
    const float4* __restrict__ xr = (const float4*)(x + (size_t)row * HW);
    float4* __restrict__ yr = (float4*)(out + (size_t)row * HW);

    const bool lastValid = (tid < (NV4 - 12 * TPB));  // tid < 256

    // ---- load entire row into registers (13 float4 / thread) ----
    float4 v[13];
#pragma unroll
    for (int j = 0; j < 12; ++j) v[j] = xr[tid + j * TPB];
    if (lastValid) v[12] = xr[tid + 12 * TPB];
    else           v[12] = make_float4(INFINITY, INFINITY, INFINITY, INFINITY);

    // ---- phase A: row min ----
    float m = INFINITY;
#pragma unroll
    for (int j = 0; j < 13; ++j)
        m = fminf(m, fminf(fminf(v[j].x, v[j].y), fminf(v[j].z, v[j].w)));
    m = waveReduceMin(m);

    __shared__ float  sminw[16];
    __shared__ double ssum[16], ssuml[16];
    __shared__ float  sparams[3];   // rmin, k, invth
    __shared__ float  scoef[8];     // series coefficients

    const int wid = tid >> 6, lane = tid & 63;
    if (lane == 0) sminw[wid] = m;
    __syncthreads();
    if (tid == 0) {
        float mm = sminw[0];
        for (int i = 1; i < 16; ++i) mm = fminf(mm, sminw[i]);
        sparams[0] = mm;
    }
    __syncthreads();
    const float rmin = sparams[0];

    // ---- phase B: sum and sum-of-log of xm = ((x - min) + 1e-7) + 1e-7 ----
    double lsum = 0.0, lsl = 0.0;
#pragma unroll
    for (int j = 0; j < 13; ++j) {
        if (j < 12 || lastValid) {
            float e0 = v[j].x, e1 = v[j].y, e2 = v[j].z, e3 = v[j].w;
            float xm0 = (e0 - rmin + 1e-7f) + 1e-7f;
            float xm1 = (e1 - rmin + 1e-7f) + 1e-7f;
            float xm2 = (e2 - rmin + 1e-7f) + 1e-7f;
            float xm3 = (e3 - rmin + 1e-7f) + 1e-7f;
            lsum += ((double)xm0 + (double)xm1) + ((double)xm2 + (double)xm3);
            lsl  += ((double)__logf(xm0) + (double)__logf(xm1))
                  + ((double)__logf(xm2) + (double)__logf(xm3));
        }
    }
    lsum = waveReduceSum(lsum);
    lsl  = waveReduceSum(lsl);
    if (lane == 0) { ssum[wid] = lsum; ssuml[wid] = lsl; }
    __syncthreads();

    // ---- per-row scalar phase (thread 0): Newton for k, Gamma(k), coefficients ----
    if (tid == 0) {
        double ts = 0.0, tl = 0.0;
        for (int i = 0; i < 16; ++i) { ts += ssum[i]; tl += ssuml[i]; }
        const double meand = ts / (double)HW;
        const double mlogd = tl / (double)HW;
        float s = (float)(log(meand) - mlogd);

        float s3 = s - 3.0f;
        float rt = sqrtf(s3 * s3 + 24.0f * s);
        float k  = (3.0f - s + rt) / (12.0f * s) + 1e-7f;
        for (int it = 0; it < 10; ++it) {
            float nm = logf(k) - digamma_f(k) - s;
            float dn = 1.0f / k - trigamma_ref(k);
            k = k - nm / dn;
        }
        // clip with NaN-propagation (comparisons false for NaN -> k stays NaN, like np.clip)
        if (k < 1e-7f) k = 1e-7f;
        if (k > 18.0f) k = 18.0f;

        // Lanczos gamma(k) in double (cancellation-safe) + series coefficients
        const double CH[8] = {676.5203681218851, -1259.1392167224028, 771.3234287776531,
                              -176.6150291621406, 12.507343278686905, -0.13857109526572012,
                              9.984369578019572e-06, 1.5056327351493116e-07};
        double z = (double)k;
        double acc = 0.9999999999998099;
        for (int i = 0; i < 8; ++i) acc += CH[i] / (z + (double)(i + 1));
        double t = z + 7.5;
        double g = 2.5066282746310002 * exp((z + 0.5) * log(t) - t) * acc / z;  // Gamma(k)

        double den = g * z;                 // Gamma * k
        scoef[0] = (float)(1.0 / den);
        for (int j = 1; j < 8; ++j) {
            den *= (z + (double)j);         // Gamma * k * (k+1) * ... * (k+j)
            scoef[j] = (float)(1.0 / den);
        }
        sparams[1] = k;
        sparams[2] = (float)((double)k / meand);   // 1/theta = k / mean
    }
    __syncthreads();

    const float kk    = sparams[1];
    const float invth = sparams[2];
    const float c0 = scoef[0], c1 = scoef[1], c2 = scoef[2], c3 = scoef[3];
    const float c4 = scoef[4], c5 = scoef[5], c6 = scoef[6], c7 = scoef[7];

    // ---- phase C: elementwise y = exp(k*ln(xq) - xq) * Horner(c, xq) ----
#pragma unroll
    for (int j = 0; j < 13; ++j) {
        if (j < 12 || lastValid) {
            float e[4] = {v[j].x, v[j].y, v[j].z, v[j].w};
            float o[4];
#pragma unroll
            for (int q = 0; q < 4; ++q) {
                float xf = e[q] - rmin + 1e-7f;
                float xq = xf * invth;
                float p = fmaf(c7, xq, c6);
                p = fmaf(p, xq, c5);
                p = fmaf(p, xq, c4);
                p = fmaf(p, xq, c3);
                p = fmaf(p, xq, c2);
                p = fmaf(p, xq, c1);
                p = fmaf(p, xq, c0);
                float tt = __expf(fmaf(kk, __logf(xq), -xq));
                float y = tt * p;
                o[q] = isfinite(y) ? y : 0.0f;
            }
            yr[tid + j * TPB] = make_float4(o[0], o[1], o[2], o[3]);
        }
    }
}

extern "C" void kernel_launch(void* const* d_in, const int* in_sizes, int n_in,
                              void* d_out, int out_size, void* d_ws, size_t ws_size,
                              hipStream_t stream) {
    const float* x = (const float*)d_in[0];
    float* out = (float*)d_out;
    const int rows = in_sizes[0] / HW;   // 256
    gamma_norm2d<<<dim3(rows), dim3(TPB), 0, stream>>>(x, out);
}